// Round 9
// baseline (473.773 us; speedup 1.0000x reference)
//
#include <hip/hip_runtime.h>
#include <math.h>

#define NCOMP 32768
#define LDIM  128
#define HDIM  512
#define DDIM  256
#define BROWS 512
#define KTOP  16

// -0.5 * D * log(2*pi)
#define NEG_HALF_D_LOG2PI (-235.24844f)

typedef short bf16x8 __attribute__((ext_vector_type(8)));
typedef float f32x4  __attribute__((ext_vector_type(4)));
typedef unsigned short ushort_t;
typedef unsigned int uint_t;
typedef unsigned long long u64_t;

// ---------------- bf16 helpers (RNE) ----------------
__device__ __forceinline__ ushort_t f2bf(float f) {
  uint_t u = __float_as_uint(f);
  u = u + 0x7fffu + ((u >> 16) & 1u);
  return (ushort_t)(u >> 16);
}
__device__ __forceinline__ float bf2f(ushort_t h) {
  return __uint_as_float(((uint_t)h) << 16);
}

// async global->LDS, 16B per lane. LDS dest is wave-uniform base + lane*16.
__device__ __forceinline__ void load_lds16(const ushort_t* g, ushort_t* l) {
  __builtin_amdgcn_global_load_lds(
      (const __attribute__((address_space(1))) unsigned int*)g,
      (__attribute__((address_space(3))) unsigned int*)l, 16, 0, 0);
}

// ------------------------------------------------------------------
// Merged prep kernel. Block ranges:
//  [0,4096)     cast z -> z16 (bf16)
//  [4096,4352)  W1 [128][512] -> W1t [512][128] bf16
//  [4352,5376)  W2 [512][512] -> W2tp [512][512] bf16, PAIRED cols:
//               cp=2d <- col d (mu), cp=2d+1 <- col 256+d (logvar);
//               block 4352 also fills b2p likewise.
//  [5376,5888)  x -> Xs [512][512] bf16, slot-permuted interleave:
//               for dim d: j=(d>>3)&3, a=d&7, slot=(d&~31)+a*4+j;
//               Xs[b][2*slot]=x_d^2 (pairs v0), [2*slot+1]=x_d (pairs v1).
// The slot permutation matches the G2 fused-epilogue store order so the
// G3 dot over k is Sum_d (x_d^2*v0_d + x_d*v1_d) exactly.
// ------------------------------------------------------------------
__global__ __launch_bounds__(256) void prep_kernel(
    const float* __restrict__ x, const float* __restrict__ z,
    const float* __restrict__ W1, const float* __restrict__ W2,
    const float* __restrict__ b2,
    ushort_t* __restrict__ z16, ushort_t* __restrict__ W1t,
    ushort_t* __restrict__ W2tp, float* __restrict__ b2p,
    ushort_t* __restrict__ Xs) {
  const int blk = blockIdx.x, tid = threadIdx.x;
  if (blk < 4096) {
    int i = (blk * 256 + tid) * 4;
    float4 v = *(const float4*)&z[i];
    z16[i + 0] = f2bf(v.x);
    z16[i + 1] = f2bf(v.y);
    z16[i + 2] = f2bf(v.z);
    z16[i + 3] = f2bf(v.w);
  } else if (blk < 4352) {
    int i = (blk - 4096) * 256 + tid;      // 128*512
    int r = i >> 9, c = i & 511;
    W1t[(size_t)c * 128 + r] = f2bf(W1[i]);
  } else if (blk < 5376) {
    int i = (blk - 4352) * 256 + tid;      // 512*512
    int h = i >> 9, c = i & 511;
    int cp = (c < 256) ? (c << 1) : (((c - 256) << 1) | 1);
    W2tp[(size_t)cp * 512 + h] = f2bf(W2[i]);
    if (blk == 4352) {
      b2p[2 * tid]     = b2[tid];
      b2p[2 * tid + 1] = b2[256 + tid];
    }
  } else {
    int i = (blk - 5376) * 256 + tid;      // 512*256
    int b = i >> 8, d = i & 255;
    float xv = x[i];
    int j = (d >> 3) & 3, a = d & 7;
    int slot = (d & ~31) + a * 4 + j;
    uint_t w = (uint_t)f2bf(xv * xv) | ((uint_t)f2bf(xv) << 16);
    *(uint_t*)(Xs + (size_t)b * 512 + 2 * slot) = w;
  }
}

// cvec[n] = sum of 8 deterministic partials + const
__global__ __launch_bounds__(256) void cvec_kernel(const float* __restrict__ cpart,
                                                   float* __restrict__ cvec) {
  int n = blockIdx.x * 256 + threadIdx.x;
  float4 a = *(const float4*)&cpart[(size_t)n * 8];
  float4 b = *(const float4*)&cpart[(size_t)n * 8 + 4];
  cvec[n] = ((a.x + a.y) + (a.z + a.w)) + ((b.x + b.y) + (b.z + b.w))
            + NEG_HALF_D_LOG2PI;
}

// ------------------------------------------------------------------
// 256x256 bf16 MFMA GEMM — round-6 2-phase structure (proven).
// BK=64, 512 threads (8 waves 2x4), double-buffered 128KB LDS,
// global_load_lds 16B with pre-swizzled source, XOR swizzle, k-half
// composed via XOR. One __syncthreads per K-step.
// EPI: 0 = relu(+bias) -> bf16 out
//      1 = +bias -> f32 out
//      2 = fused params epilogue (paired mu/logvar cols): writes Ps
//          (hi|lo split slabs, slot-permuted interleave) + cpart slots.
// ------------------------------------------------------------------
template<int EPI>
__global__ __launch_bounds__(512, 2) void gemm256(
    const ushort_t* __restrict__ A, int lda,
    const ushort_t* __restrict__ B, int ldb,
    const float* __restrict__ bias,
    void* __restrict__ Cout, int ldc,
    float* __restrict__ cpart,
    int nsteps, int sps,
    int kbA0, int kbA1, int kbA2,
    int kbB0, int kbB1, int kbB2,
    int nShort, int shortIsM) {
  __shared__ __align__(16) ushort_t As[2][16384];   // 32KB per buffer
  __shared__ __align__(16) ushort_t Bs[2][16384];

  const int tid = threadIdx.x;
  const int lane = tid & 63, wid = tid >> 6;
  const int wr = wid >> 2, wc = wid & 3;            // 2 x 4 wave grid

  // XCD-chunked bijective block swizzle (gridDim.x % 8 == 0)
  const int cpx = gridDim.x >> 3;
  const int newid = (blockIdx.x & 7) * cpx + (blockIdx.x >> 3);
  const int s = newid % nShort, l = newid / nShort;
  const int m0 = (shortIsM ? s : l) * 256;
  const int n0 = (shortIsM ? l : s) * 256;

  // ---- staging: 4 rounds per matrix; dest chunk p = r*512+tid (16B) ----
  const ushort_t* pA[4];
  const ushort_t* pB[4];
  #pragma unroll
  for (int r = 0; r < 4; r++) {
    int p = r * 512 + tid;
    int row = p >> 3;
    int col = ((p & 7) ^ (row & 7)) * 8;
    pA[r] = A + (size_t)(m0 + row) * lda + col;
    pB[r] = B + (size_t)(n0 + row) * ldb + col;
  }

  // ---- fragment read byte-offsets (swizzled); k-half composed via XOR ----
  int aoff[8], boff[4];
  #pragma unroll
  for (int i = 0; i < 8; i++) {
    int ra = wr * 128 + i * 16 + (lane & 15);
    aoff[i] = (ra * 128 + ((lane >> 4) * 16)) ^ ((ra & 7) << 4);
  }
  #pragma unroll
  for (int j = 0; j < 4; j++) {
    int rb = wc * 64 + j * 16 + (lane & 15);
    boff[j] = (rb * 128 + ((lane >> 4) * 16)) ^ ((rb & 7) << 4);
  }

  f32x4 acc[8][4];
  #pragma unroll
  for (int i = 0; i < 8; i++)
    #pragma unroll
    for (int j = 0; j < 4; j++)
      acc[i][j] = (f32x4){0.f, 0.f, 0.f, 0.f};

  auto stage = [&](int buf, int step) {
    int sg = (step >= sps) ? ((step >= 2 * sps) ? 2 : 1) : 0;
    int ks = (step - sg * sps) << 6;
    int kA = ((sg == 0) ? kbA0 : (sg == 1) ? kbA1 : kbA2) + ks;
    int kB = ((sg == 0) ? kbB0 : (sg == 1) ? kbB1 : kbB2) + ks;
    #pragma unroll
    for (int r = 0; r < 4; r++) {
      load_lds16(pA[r] + kA, &As[buf][(r * 512 + tid) * 8]);
      load_lds16(pB[r] + kB, &Bs[buf][(r * 512 + tid) * 8]);
    }
  };

  stage(0, 0);
  __syncthreads();              // vmcnt drain -> buf0 ready

  int cur = 0;
  for (int step = 0; step < nsteps; ++step) {
    if (step + 1 < nsteps) stage(cur ^ 1, step + 1);   // loads fly over compute

    const char* Ab = (const char*)As[cur];
    const char* Bb = (const char*)Bs[cur];
    #pragma unroll
    for (int kh = 0; kh < 2; ++kh) {
      bf16x8 af[8], bfr[4];
      #pragma unroll
      for (int i = 0; i < 8; i++) af[i] = *(const bf16x8*)(Ab + (aoff[i] ^ (kh << 6)));
      #pragma unroll
      for (int j = 0; j < 4; j++) bfr[j] = *(const bf16x8*)(Bb + (boff[j] ^ (kh << 6)));
      #pragma unroll
      for (int i = 0; i < 8; i++)
        #pragma unroll
        for (int j = 0; j < 4; j++)
          acc[i][j] = __builtin_amdgcn_mfma_f32_16x16x32_bf16(af[i], bfr[j], acc[i][j], 0, 0, 0);
    }
    __syncthreads();            // drains vmcnt (next buf ready) + lgkm
    cur ^= 1;
  }

  // ---- epilogue ----
  float bv[4];
  #pragma unroll
  for (int j = 0; j < 4; j++)
    bv[j] = bias[n0 + wc * 64 + j * 16 + (lane & 15)];

  if (EPI == 2) {
    // Fused params epilogue. Even lane holds mu (col cp even), odd holds
    // logvar for the SAME (n, d) — partner via shfl_xor(1). Even lane
    // computes v0=-0.5/var, v1=mu/var, hi/lo bf16 split, and stores
    // (v0,v1) pairs for j=0..3 as one uint4 into the slot-permuted Ps;
    // cpart slot gets the deterministic partial of cvec.
    uint_t* P32 = (uint_t*)Cout;
    const int a = (lane & 15) >> 1;
    const int slotbase = (n0 >> 1) + wc * 32 + a * 4;
    #pragma unroll
    for (int i = 0; i < 8; i++) {
      #pragma unroll
      for (int r = 0; r < 4; r++) {
        float vj[4], pr[4];
        #pragma unroll
        for (int j = 0; j < 4; j++) vj[j] = acc[i][j][r] + bv[j];
        #pragma unroll
        for (int j = 0; j < 4; j++) pr[j] = __shfl_xor(vj[j], 1, 64);
        float term = 0.f;
        uint_t hiw[4], low[4];
        #pragma unroll
        for (int j = 0; j < 4; j++) {
          float mu = vj[j], lv = pr[j];
          float sp = (lv > 20.f) ? lv : log1pf(expf(lv));
          float sd = fminf(sp + 0.1f, 1.0f);
          float iv = 1.0f / (sd * sd);
          float v0 = -0.5f * iv, v1 = mu * iv;
          ushort_t h0 = f2bf(v0), h1 = f2bf(v1);
          hiw[j] = (uint_t)h0 | ((uint_t)h1 << 16);
          low[j] = (uint_t)f2bf(v0 - bf2f(h0)) | ((uint_t)f2bf(v1 - bf2f(h1)) << 16);
          term += -0.5f * mu * mu * iv - logf(sd);
        }
        term += __shfl_xor(term, 2, 64);
        term += __shfl_xor(term, 4, 64);
        term += __shfl_xor(term, 8, 64);
        int n = m0 + wr * 128 + i * 16 + ((lane >> 4) << 2) + r;
        if ((lane & 1) == 0) {
          size_t base = (size_t)n * 512 + slotbase;
          *(uint4*)(P32 + base)       = make_uint4(hiw[0], hiw[1], hiw[2], hiw[3]);
          *(uint4*)(P32 + base + 256) = make_uint4(low[0], low[1], low[2], low[3]);
          if ((lane & 15) == 0)
            cpart[(size_t)n * 8 + (n0 >> 8) * 4 + wc] = term;
        }
      }
    }
    return;
  }

  #pragma unroll
  for (int i = 0; i < 8; i++) {
    int rowb = m0 + wr * 128 + i * 16 + ((lane >> 4) << 2);
    #pragma unroll
    for (int r = 0; r < 4; r++) {
      #pragma unroll
      for (int j = 0; j < 4; j++) {
        int col = n0 + wc * 64 + j * 16 + (lane & 15);
        float v = acc[i][j][r] + bv[j];
        if (EPI == 0) {
          v = fmaxf(v, 0.f);
          ((ushort_t*)Cout)[(size_t)(rowb + r) * ldc + col] = f2bf(v);
        } else {
          ((float*)Cout)[(size_t)(rowb + r) * ldc + col] = v;
        }
      }
    }
  }
}

// ------------------------------------------------------------------
// Top-16: wave-cooperative ballot-filtered select (unchanged, verified).
// ------------------------------------------------------------------
__device__ __forceinline__ u64_t shfl_up1_u64(u64_t v) {
  uint_t lo = (uint_t)v, hi = (uint_t)(v >> 32);
  lo = __shfl_up(lo, 1, 64); hi = __shfl_up(hi, 1, 64);
  return ((u64_t)hi << 32) | lo;
}
__device__ __forceinline__ u64_t shfl_u64(u64_t v, int src) {
  uint_t lo = (uint_t)v, hi = (uint_t)(v >> 32);
  lo = __shfl(lo, src, 64); hi = __shfl(hi, src, 64);
  return ((u64_t)hi << 32) | lo;
}
__device__ __forceinline__ void insert_step(u64_t& key, u64_t cand, int lane) {
  u64_t kup = shfl_up1_u64(key);
  if (lane == 0) kup = ~0ULL;
  if (cand > key) key = (cand > kup) ? kup : cand;
}

__global__ __launch_bounds__(256) void topk_kernel(const float* __restrict__ lp,
                                                   const float* __restrict__ log_w,
                                                   float* __restrict__ out) {
  const int b = blockIdx.x;
  const int tid = threadIdx.x;
  const int w = tid >> 6, lane = tid & 63;
  const float* row = lp + (size_t)b * NCOMP;

  u64_t key = 0;
  u64_t theta = 0;

  const int base = w * 8192;
  for (int c = 0; c < 32; ++c) {
    int n0 = base + c * 256 + lane * 4;
    float4 s4 = *(const float4*)&row[n0];
    float4 w4 = *(const float4*)&log_w[n0];
    float ss[4] = {s4.x + w4.x, s4.y + w4.y, s4.z + w4.z, s4.w + w4.w};
    #pragma unroll
    for (int e = 0; e < 4; e++) {
      uint_t u = __float_as_uint(ss[e]);
      u = (u & 0x80000000u) ? ~u : (u | 0x80000000u);
      u64_t k = ((u64_t)u << 32) | (u64_t)(0xFFFFFFFFu - (uint_t)(n0 + e));
      u64_t m = __ballot(k > theta);
      if (m) {
        do {
          int src = __ffsll((long long)m) - 1;
          m &= m - 1;
          u64_t cand = shfl_u64(k, src);
          insert_step(key, cand, lane);
        } while (m);
        theta = shfl_u64(key, 15);
      }
    }
  }

  __shared__ u64_t sk[64];
  if (lane < 16) sk[w * 16 + lane] = key;
  __syncthreads();
  if (w == 0) {
    u64_t th = shfl_u64(key, 15);
    for (int t = 16; t < 64; ++t) {
      u64_t cand = sk[t];
      if (cand > th) {
        insert_step(key, cand, lane);
        th = shfl_u64(key, 15);
      }
    }
    if (lane < 16) {
      uint_t idx = 0xFFFFFFFFu - (uint_t)key;
      out[(size_t)b * KTOP + lane] = row[idx];
    }
  }
}

// ------------------------------------------------------------------
extern "C" void kernel_launch(void* const* d_in, const int* in_sizes, int n_in,
                              void* d_out, int out_size, void* d_ws, size_t ws_size,
                              hipStream_t stream) {
  const float* x     = (const float*)d_in[0];
  const float* log_w = (const float*)d_in[1];
  const float* z     = (const float*)d_in[2];
  const float* W1    = (const float*)d_in[3];
  const float* b1    = (const float*)d_in[4];
  const float* W2    = (const float*)d_in[5];
  const float* b2    = (const float*)d_in[6];
  float* out = (float*)d_out;

  char* p = (char*)d_ws;
  float* lp     = (float*)p;    p += (size_t)BROWS * NCOMP * 4;   // 64MB
  float* cvec   = (float*)p;    p += (size_t)NCOMP * 4;
  float* cpart  = (float*)p;    p += (size_t)NCOMP * 8 * 4;       // 1MB
  ushort_t* Ps  = (ushort_t*)p; p += (size_t)NCOMP * 1024 * 2;    // 64MB
  ushort_t* h16 = (ushort_t*)p; p += (size_t)NCOMP * 512 * 2;     // 32MB
  ushort_t* z16 = (ushort_t*)p; p += (size_t)NCOMP * 128 * 2;     // 8MB
  ushort_t* W1t = (ushort_t*)p; p += (size_t)512 * 128 * 2;
  ushort_t* W2tp= (ushort_t*)p; p += (size_t)512 * 512 * 2;
  float* b2p    = (float*)p;    p += (size_t)512 * 4;
  ushort_t* Xs  = (ushort_t*)p; p += (size_t)512 * 512 * 2;

  // prep (merged): z16, W1t, W2tp (paired), b2p, Xs (slot-permuted)
  hipLaunchKernelGGL(prep_kernel, dim3(5888), dim3(256), 0, stream,
                     x, z, W1, W2, b2, z16, W1t, W2tp, b2p, Xs);

  // G1: h16 = relu(z16 @ W1t^T + b1)   [32768,128] x [512,128]^T
  hipLaunchKernelGGL((gemm256<0>), dim3(256), dim3(512), 0, stream,
                     z16, LDIM, W1t, LDIM, b1, h16, HDIM, (float*)nullptr,
                     2, 2, 0, 0, 0, 0, 0, 0, 2, 0);
  // G2 fused: raw = h16 @ W2tp^T + b2p -> params transform in epilogue
  //           writes Ps (slot-permuted hi|lo) + cpart
  hipLaunchKernelGGL((gemm256<2>), dim3(256), dim3(512), 0, stream,
                     h16, HDIM, W2tp, HDIM, b2p, Ps, 1024, cpart,
                     8, 8, 0, 0, 0, 0, 0, 0, 2, 0);
  // cvec = sum(cpart slots) + const
  hipLaunchKernelGGL(cvec_kernel, dim3(NCOMP / 256), dim3(256), 0, stream,
                     cpart, cvec);
  // G3: lp = Xs @ Ps^T + cvec  (split-bf16, A-lo dropped: uh*vh + uh*vl)
  //     K=1024: A segs {0,0} (hi,hi); B segs {0,512} (hi,lo); nt=16
  hipLaunchKernelGGL((gemm256<1>), dim3(256), dim3(512), 0, stream,
                     Xs, 512, Ps, 1024, cvec, lp, NCOMP, (float*)nullptr,
                     16, 8, 0, 0, 0, 0, 512, 0, 2, 1);
  // topk
  hipLaunchKernelGGL(topk_kernel, dim3(BROWS), dim3(256), 0, stream, lp, log_w, out);
}

// Round 10
// 386.520 us; speedup vs baseline: 1.2257x; 1.2257x over previous
//
#include <hip/hip_runtime.h>
#include <math.h>

#define NCOMP 32768
#define LDIM  128
#define HDIM  512
#define DDIM  256
#define BROWS 512
#define KTOP  16

// -0.5 * D * log(2*pi)
#define NEG_HALF_D_LOG2PI (-235.24844f)

typedef short bf16x8 __attribute__((ext_vector_type(8)));
typedef float f32x4  __attribute__((ext_vector_type(4)));
typedef unsigned short ushort_t;
typedef unsigned int uint_t;
typedef unsigned long long u64_t;

// ---------------- bf16 helpers (RNE) ----------------
__device__ __forceinline__ ushort_t f2bf(float f) {
  uint_t u = __float_as_uint(f);
  u = u + 0x7fffu + ((u >> 16) & 1u);
  return (ushort_t)(u >> 16);
}
__device__ __forceinline__ float bf2f(ushort_t h) {
  return __uint_as_float(((uint_t)h) << 16);
}

// async global->LDS, 16B per lane. LDS dest is wave-uniform base + lane*16.
__device__ __forceinline__ void load_lds16(const ushort_t* g, ushort_t* l) {
  __builtin_amdgcn_global_load_lds(
      (const __attribute__((address_space(1))) unsigned int*)g,
      (__attribute__((address_space(3))) unsigned int*)l, 16, 0, 0);
}

// ------------------------------------------------------------------
// Merged prep kernel. Block ranges:
//  [0,4096)     cast z -> z16 (bf16)
//  [4096,4352)  W1 [128][512] -> W1t [512][128] bf16
//  [4352,5376)  W2 [512][512] -> W2tp [512][512] bf16, PAIRED cols:
//               cp=2d <- col d (mu), cp=2d+1 <- col 256+d (logvar);
//               block 4352 also fills b2p likewise.
//  [5376,5888)  x -> Xs [512][512] bf16, slot-permuted interleave:
//               for dim d: j=(d>>3)&3, a=d&7, slot=(d&~31)+a*4+j;
//               Xs[b][2*slot]=x_d^2 (pairs v0), [2*slot+1]=x_d (pairs v1).
// Slot permutation matches the G2 fused-epilogue store order (verified:
// round 9 passed with identical layout).
// ------------------------------------------------------------------
__global__ __launch_bounds__(256) void prep_kernel(
    const float* __restrict__ x, const float* __restrict__ z,
    const float* __restrict__ W1, const float* __restrict__ W2,
    const float* __restrict__ b2,
    ushort_t* __restrict__ z16, ushort_t* __restrict__ W1t,
    ushort_t* __restrict__ W2tp, float* __restrict__ b2p,
    ushort_t* __restrict__ Xs) {
  const int blk = blockIdx.x, tid = threadIdx.x;
  if (blk < 4096) {
    int i = (blk * 256 + tid) * 4;
    float4 v = *(const float4*)&z[i];
    z16[i + 0] = f2bf(v.x);
    z16[i + 1] = f2bf(v.y);
    z16[i + 2] = f2bf(v.z);
    z16[i + 3] = f2bf(v.w);
  } else if (blk < 4352) {
    int i = (blk - 4096) * 256 + tid;      // 128*512
    int r = i >> 9, c = i & 511;
    W1t[(size_t)c * 128 + r] = f2bf(W1[i]);
  } else if (blk < 5376) {
    int i = (blk - 4352) * 256 + tid;      // 512*512
    int h = i >> 9, c = i & 511;
    int cp = (c < 256) ? (c << 1) : (((c - 256) << 1) | 1);
    W2tp[(size_t)cp * 512 + h] = f2bf(W2[i]);
    if (blk == 4352) {
      b2p[2 * tid]     = b2[tid];
      b2p[2 * tid + 1] = b2[256 + tid];
    }
  } else {
    int i = (blk - 5376) * 256 + tid;      // 512*256
    int b = i >> 8, d = i & 255;
    float xv = x[i];
    int j = (d >> 3) & 3, a = d & 7;
    int slot = (d & ~31) + a * 4 + j;
    uint_t w = (uint_t)f2bf(xv * xv) | ((uint_t)f2bf(xv) << 16);
    *(uint_t*)(Xs + (size_t)b * 512 + 2 * slot) = w;
  }
}

// cvec[n] = sum of 8 deterministic partials + const
__global__ __launch_bounds__(256) void cvec_kernel(const float* __restrict__ cpart,
                                                   float* __restrict__ cvec) {
  int n = blockIdx.x * 256 + threadIdx.x;
  float4 a = *(const float4*)&cpart[(size_t)n * 8];
  float4 b = *(const float4*)&cpart[(size_t)n * 8 + 4];
  cvec[n] = ((a.x + a.y) + (a.z + a.w)) + ((b.x + b.y) + (b.z + b.w))
            + NEG_HALF_D_LOG2PI;
}

// ------------------------------------------------------------------
// 256x256 bf16 MFMA GEMM — round-6 2-phase structure (proven).
// EPI: 0 = relu(+bias) -> bf16 out
//      1 = +bias -> f32 out
//      2 = fused params epilogue — FULLY MACRO-UNROLLED, every index a
//          literal, no local arrays (rule #20: dynamic indexing of the
//          AGPR acc array forces a scratch spill of the whole main loop;
//          that was round 9's 10x regression).
// ------------------------------------------------------------------
template<int EPI>
__global__ __launch_bounds__(512, 2) void gemm256(
    const ushort_t* __restrict__ A, int lda,
    const ushort_t* __restrict__ B, int ldb,
    const float* __restrict__ bias,
    void* __restrict__ Cout, int ldc,
    float* __restrict__ cpart,
    int nsteps, int sps,
    int kbA0, int kbA1, int kbA2,
    int kbB0, int kbB1, int kbB2,
    int nShort, int shortIsM) {
  __shared__ __align__(16) ushort_t As[2][16384];   // 32KB per buffer
  __shared__ __align__(16) ushort_t Bs[2][16384];

  const int tid = threadIdx.x;
  const int lane = tid & 63, wid = tid >> 6;
  const int wr = wid >> 2, wc = wid & 3;            // 2 x 4 wave grid

  // XCD-chunked bijective block swizzle (gridDim.x % 8 == 0)
  const int cpx = gridDim.x >> 3;
  const int newid = (blockIdx.x & 7) * cpx + (blockIdx.x >> 3);
  const int s = newid % nShort, l = newid / nShort;
  const int m0 = (shortIsM ? s : l) * 256;
  const int n0 = (shortIsM ? l : s) * 256;

  // ---- staging: 4 rounds per matrix; dest chunk p = r*512+tid (16B) ----
  const ushort_t* pA[4];
  const ushort_t* pB[4];
  #pragma unroll
  for (int r = 0; r < 4; r++) {
    int p = r * 512 + tid;
    int row = p >> 3;
    int col = ((p & 7) ^ (row & 7)) * 8;
    pA[r] = A + (size_t)(m0 + row) * lda + col;
    pB[r] = B + (size_t)(n0 + row) * ldb + col;
  }

  // ---- fragment read byte-offsets (swizzled); k-half composed via XOR ----
  int aoff[8], boff[4];
  #pragma unroll
  for (int i = 0; i < 8; i++) {
    int ra = wr * 128 + i * 16 + (lane & 15);
    aoff[i] = (ra * 128 + ((lane >> 4) * 16)) ^ ((ra & 7) << 4);
  }
  #pragma unroll
  for (int j = 0; j < 4; j++) {
    int rb = wc * 64 + j * 16 + (lane & 15);
    boff[j] = (rb * 128 + ((lane >> 4) * 16)) ^ ((rb & 7) << 4);
  }

  f32x4 acc[8][4];
  #pragma unroll
  for (int i = 0; i < 8; i++)
    #pragma unroll
    for (int j = 0; j < 4; j++)
      acc[i][j] = (f32x4){0.f, 0.f, 0.f, 0.f};

  auto stage = [&](int buf, int step) {
    int sg = (step >= sps) ? ((step >= 2 * sps) ? 2 : 1) : 0;
    int ks = (step - sg * sps) << 6;
    int kA = ((sg == 0) ? kbA0 : (sg == 1) ? kbA1 : kbA2) + ks;
    int kB = ((sg == 0) ? kbB0 : (sg == 1) ? kbB1 : kbB2) + ks;
    #pragma unroll
    for (int r = 0; r < 4; r++) {
      load_lds16(pA[r] + kA, &As[buf][(r * 512 + tid) * 8]);
      load_lds16(pB[r] + kB, &Bs[buf][(r * 512 + tid) * 8]);
    }
  };

  stage(0, 0);
  __syncthreads();              // vmcnt drain -> buf0 ready

  int cur = 0;
  for (int step = 0; step < nsteps; ++step) {
    if (step + 1 < nsteps) stage(cur ^ 1, step + 1);   // loads fly over compute

    const char* Ab = (const char*)As[cur];
    const char* Bb = (const char*)Bs[cur];
    #pragma unroll
    for (int kh = 0; kh < 2; ++kh) {
      bf16x8 af[8], bfr[4];
      #pragma unroll
      for (int i = 0; i < 8; i++) af[i] = *(const bf16x8*)(Ab + (aoff[i] ^ (kh << 6)));
      #pragma unroll
      for (int j = 0; j < 4; j++) bfr[j] = *(const bf16x8*)(Bb + (boff[j] ^ (kh << 6)));
      #pragma unroll
      for (int i = 0; i < 8; i++)
        #pragma unroll
        for (int j = 0; j < 4; j++)
          acc[i][j] = __builtin_amdgcn_mfma_f32_16x16x32_bf16(af[i], bfr[j], acc[i][j], 0, 0, 0);
    }
    __syncthreads();            // drains vmcnt (next buf ready) + lgkm
    cur ^= 1;
  }

  // ---- epilogue ----
  float bv[4];
  #pragma unroll
  for (int j = 0; j < 4; j++)
    bv[j] = bias[n0 + wc * 64 + j * 16 + (lane & 15)];

  if (EPI == 2) {
    uint_t* P32 = (uint_t*)Cout;
    const int aa = (lane & 15) >> 1;
    const int slotbase = (n0 >> 1) + wc * 32 + aa * 4;
    const int nbase = m0 + wr * 128 + ((lane >> 4) << 2);
    const float bv0 = bv[0], bv1 = bv[1], bv2 = bv[2], bv3 = bv[3];
    const bool evenlane = ((lane & 1) == 0);
    const bool lead = ((lane & 15) == 0);
    const int cslot = (n0 >> 8) * 4 + wc;

#define XFORM(MU, LV, HIW, LOW, TERM) {                                   \
    float sp_ = log1pf(expf(LV));                                         \
    float sd_ = fminf(sp_ + 0.1f, 1.0f);                                  \
    float iv_ = 1.0f / (sd_ * sd_);                                       \
    float v0_ = -0.5f * iv_, v1_ = (MU) * iv_;                            \
    ushort_t h0_ = f2bf(v0_), h1_ = f2bf(v1_);                            \
    HIW = (uint_t)h0_ | ((uint_t)h1_ << 16);                              \
    LOW = (uint_t)f2bf(v0_ - bf2f(h0_)) |                                 \
          ((uint_t)f2bf(v1_ - bf2f(h1_)) << 16);                          \
    TERM += -0.5f * (MU) * (MU) * iv_ - logf(sd_);                        \
  }

#define EPIR(I, R) {                                                      \
    float m0_ = acc[I][0][R] + bv0;                                       \
    float m1_ = acc[I][1][R] + bv1;                                       \
    float m2_ = acc[I][2][R] + bv2;                                       \
    float m3_ = acc[I][3][R] + bv3;                                       \
    float q0_ = __shfl_xor(m0_, 1, 64);                                   \
    float q1_ = __shfl_xor(m1_, 1, 64);                                   \
    float q2_ = __shfl_xor(m2_, 1, 64);                                   \
    float q3_ = __shfl_xor(m3_, 1, 64);                                   \
    float term_ = 0.f;                                                    \
    uint_t hw0_, hw1_, hw2_, hw3_, lw0_, lw1_, lw2_, lw3_;                \
    XFORM(m0_, q0_, hw0_, lw0_, term_);                                   \
    XFORM(m1_, q1_, hw1_, lw1_, term_);                                   \
    XFORM(m2_, q2_, hw2_, lw2_, term_);                                   \
    XFORM(m3_, q3_, hw3_, lw3_, term_);                                   \
    term_ += __shfl_xor(term_, 2, 64);                                    \
    term_ += __shfl_xor(term_, 4, 64);                                    \
    term_ += __shfl_xor(term_, 8, 64);                                    \
    int n_ = nbase + (I) * 16 + (R);                                      \
    if (evenlane) {                                                       \
      size_t base_ = (size_t)n_ * 512 + slotbase;                         \
      *(uint4*)(P32 + base_)       = make_uint4(hw0_, hw1_, hw2_, hw3_);  \
      *(uint4*)(P32 + base_ + 256) = make_uint4(lw0_, lw1_, lw2_, lw3_);  \
      if (lead) cpart[(size_t)n_ * 8 + cslot] = term_;                    \
    }                                                                     \
  }

    EPIR(0,0) EPIR(0,1) EPIR(0,2) EPIR(0,3)
    EPIR(1,0) EPIR(1,1) EPIR(1,2) EPIR(1,3)
    EPIR(2,0) EPIR(2,1) EPIR(2,2) EPIR(2,3)
    EPIR(3,0) EPIR(3,1) EPIR(3,2) EPIR(3,3)
    EPIR(4,0) EPIR(4,1) EPIR(4,2) EPIR(4,3)
    EPIR(5,0) EPIR(5,1) EPIR(5,2) EPIR(5,3)
    EPIR(6,0) EPIR(6,1) EPIR(6,2) EPIR(6,3)
    EPIR(7,0) EPIR(7,1) EPIR(7,2) EPIR(7,3)
#undef EPIR
#undef XFORM
    return;
  }

  #pragma unroll
  for (int i = 0; i < 8; i++) {
    int rowb = m0 + wr * 128 + i * 16 + ((lane >> 4) << 2);
    #pragma unroll
    for (int r = 0; r < 4; r++) {
      #pragma unroll
      for (int j = 0; j < 4; j++) {
        int col = n0 + wc * 64 + j * 16 + (lane & 15);
        float v = acc[i][j][r] + bv[j];
        if (EPI == 0) {
          v = fmaxf(v, 0.f);
          ((ushort_t*)Cout)[(size_t)(rowb + r) * ldc + col] = f2bf(v);
        } else {
          ((float*)Cout)[(size_t)(rowb + r) * ldc + col] = v;
        }
      }
    }
  }
}

// ------------------------------------------------------------------
// Top-16: wave-cooperative ballot-filtered select (unchanged, verified).
// ------------------------------------------------------------------
__device__ __forceinline__ u64_t shfl_up1_u64(u64_t v) {
  uint_t lo = (uint_t)v, hi = (uint_t)(v >> 32);
  lo = __shfl_up(lo, 1, 64); hi = __shfl_up(hi, 1, 64);
  return ((u64_t)hi << 32) | lo;
}
__device__ __forceinline__ u64_t shfl_u64(u64_t v, int src) {
  uint_t lo = (uint_t)v, hi = (uint_t)(v >> 32);
  lo = __shfl(lo, src, 64); hi = __shfl(hi, src, 64);
  return ((u64_t)hi << 32) | lo;
}
__device__ __forceinline__ void insert_step(u64_t& key, u64_t cand, int lane) {
  u64_t kup = shfl_up1_u64(key);
  if (lane == 0) kup = ~0ULL;
  if (cand > key) key = (cand > kup) ? kup : cand;
}

__global__ __launch_bounds__(256) void topk_kernel(const float* __restrict__ lp,
                                                   const float* __restrict__ log_w,
                                                   float* __restrict__ out) {
  const int b = blockIdx.x;
  const int tid = threadIdx.x;
  const int w = tid >> 6, lane = tid & 63;
  const float* row = lp + (size_t)b * NCOMP;

  u64_t key = 0;
  u64_t theta = 0;

  const int base = w * 8192;
  for (int c = 0; c < 32; ++c) {
    int n0 = base + c * 256 + lane * 4;
    float4 s4 = *(const float4*)&row[n0];
    float4 w4 = *(const float4*)&log_w[n0];
    float ss[4] = {s4.x + w4.x, s4.y + w4.y, s4.z + w4.z, s4.w + w4.w};
    #pragma unroll
    for (int e = 0; e < 4; e++) {
      uint_t u = __float_as_uint(ss[e]);
      u = (u & 0x80000000u) ? ~u : (u | 0x80000000u);
      u64_t k = ((u64_t)u << 32) | (u64_t)(0xFFFFFFFFu - (uint_t)(n0 + e));
      u64_t m = __ballot(k > theta);
      if (m) {
        do {
          int src = __ffsll((long long)m) - 1;
          m &= m - 1;
          u64_t cand = shfl_u64(k, src);
          insert_step(key, cand, lane);
        } while (m);
        theta = shfl_u64(key, 15);
      }
    }
  }

  __shared__ u64_t sk[64];
  if (lane < 16) sk[w * 16 + lane] = key;
  __syncthreads();
  if (w == 0) {
    u64_t th = shfl_u64(key, 15);
    for (int t = 16; t < 64; ++t) {
      u64_t cand = sk[t];
      if (cand > th) {
        insert_step(key, cand, lane);
        th = shfl_u64(key, 15);
      }
    }
    if (lane < 16) {
      uint_t idx = 0xFFFFFFFFu - (uint_t)key;
      out[(size_t)b * KTOP + lane] = row[idx];
    }
  }
}

// ------------------------------------------------------------------
extern "C" void kernel_launch(void* const* d_in, const int* in_sizes, int n_in,
                              void* d_out, int out_size, void* d_ws, size_t ws_size,
                              hipStream_t stream) {
  const float* x     = (const float*)d_in[0];
  const float* log_w = (const float*)d_in[1];
  const float* z     = (const float*)d_in[2];
  const float* W1    = (const float*)d_in[3];
  const float* b1    = (const float*)d_in[4];
  const float* W2    = (const float*)d_in[5];
  const float* b2    = (const float*)d_in[6];
  float* out = (float*)d_out;

  char* p = (char*)d_ws;
  float* lp     = (float*)p;    p += (size_t)BROWS * NCOMP * 4;   // 64MB
  float* cvec   = (float*)p;    p += (size_t)NCOMP * 4;
  float* cpart  = (float*)p;    p += (size_t)NCOMP * 8 * 4;       // 1MB
  ushort_t* Ps  = (ushort_t*)p; p += (size_t)NCOMP * 1024 * 2;    // 64MB
  ushort_t* h16 = (ushort_t*)p; p += (size_t)NCOMP * 512 * 2;     // 32MB
  ushort_t* z16 = (ushort_t*)p; p += (size_t)NCOMP * 128 * 2;     // 8MB
  ushort_t* W1t = (ushort_t*)p; p += (size_t)512 * 128 * 2;
  ushort_t* W2tp= (ushort_t*)p; p += (size_t)512 * 512 * 2;
  float* b2p    = (float*)p;    p += (size_t)512 * 4;
  ushort_t* Xs  = (ushort_t*)p; p += (size_t)512 * 512 * 2;

  // prep (merged): z16, W1t, W2tp (paired), b2p, Xs (slot-permuted)
  hipLaunchKernelGGL(prep_kernel, dim3(5888), dim3(256), 0, stream,
                     x, z, W1, W2, b2, z16, W1t, W2tp, b2p, Xs);

  // G1: h16 = relu(z16 @ W1t^T + b1)   [32768,128] x [512,128]^T
  hipLaunchKernelGGL((gemm256<0>), dim3(256), dim3(512), 0, stream,
                     z16, LDIM, W1t, LDIM, b1, h16, HDIM, (float*)nullptr,
                     2, 2, 0, 0, 0, 0, 0, 0, 2, 0);
  // G2 fused: raw = h16 @ W2tp^T + b2p -> params transform in epilogue
  //           writes Ps (slot-permuted hi|lo) + cpart
  hipLaunchKernelGGL((gemm256<2>), dim3(256), dim3(512), 0, stream,
                     h16, HDIM, W2tp, HDIM, b2p, Ps, 1024, cpart,
                     8, 8, 0, 0, 0, 0, 0, 0, 2, 0);
  // cvec = sum(cpart slots) + const
  hipLaunchKernelGGL(cvec_kernel, dim3(NCOMP / 256), dim3(256), 0, stream,
                     cpart, cvec);
  // G3: lp = Xs @ Ps^T + cvec  (split-bf16, A-lo dropped: uh*vh + uh*vl)
  //     K=1024: A segs {0,0} (hi,hi); B segs {0,512} (hi,lo); nt=16
  hipLaunchKernelGGL((gemm256<1>), dim3(256), dim3(512), 0, stream,
                     Xs, 512, Ps, 1024, cvec, lp, NCOMP, (float*)nullptr,
                     16, 8, 0, 0, 0, 0, 512, 0, 2, 1);
  // topk
  hipLaunchKernelGGL(topk_kernel, dim3(BROWS), dim3(256), 0, stream, lp, log_w, out);
}

// Round 11
// 205.951 us; speedup vs baseline: 2.3004x; 1.8768x over previous
//
#include <hip/hip_runtime.h>
#include <math.h>

#define NCOMP 32768
#define LDIM  128
#define HDIM  512
#define DDIM  256
#define BROWS 512
#define KTOP  16

// -0.5 * D * log(2*pi)
#define NEG_HALF_D_LOG2PI (-235.24844f)

typedef short bf16x8 __attribute__((ext_vector_type(8)));
typedef float f32x4  __attribute__((ext_vector_type(4)));
typedef unsigned short ushort_t;
typedef unsigned int uint_t;
typedef unsigned long long u64_t;

// ---------------- bf16 helpers (RNE) ----------------
__device__ __forceinline__ ushort_t f2bf(float f) {
  uint_t u = __float_as_uint(f);
  u = u + 0x7fffu + ((u >> 16) & 1u);
  return (ushort_t)(u >> 16);
}
__device__ __forceinline__ float bf2f(ushort_t h) {
  return __uint_as_float(((uint_t)h) << 16);
}

// async global->LDS, 16B per lane. LDS dest is wave-uniform base + lane*16.
__device__ __forceinline__ void load_lds16(const ushort_t* g, ushort_t* l) {
  __builtin_amdgcn_global_load_lds(
      (const __attribute__((address_space(1))) unsigned int*)g,
      (__attribute__((address_space(3))) unsigned int*)l, 16, 0, 0);
}

// ------------------------------------------------------------------
// Merged prep kernel (round-8 layouts). Block ranges:
//  [0,4096)     cast z -> z16 bf16
//  [4096,4352)  W1 [128][512] -> W1t [512][128] bf16
//  [4352,5376)  W2 [512][512] -> W2t [512][512] bf16 (plain transpose)
//  [5376,5888)  x -> Xs [512][512] bf16: [x^2 (256) | x (256)]
// ------------------------------------------------------------------
__global__ __launch_bounds__(256) void prep_kernel(
    const float* __restrict__ x, const float* __restrict__ z,
    const float* __restrict__ W1, const float* __restrict__ W2,
    ushort_t* __restrict__ z16, ushort_t* __restrict__ W1t,
    ushort_t* __restrict__ W2t, ushort_t* __restrict__ Xs) {
  const int blk = blockIdx.x, tid = threadIdx.x;
  if (blk < 4096) {
    int i = (blk * 256 + tid) * 4;
    float4 v = *(const float4*)&z[i];
    z16[i + 0] = f2bf(v.x);
    z16[i + 1] = f2bf(v.y);
    z16[i + 2] = f2bf(v.z);
    z16[i + 3] = f2bf(v.w);
  } else if (blk < 4352) {
    int i = (blk - 4096) * 256 + tid;      // 128*512
    int r = i >> 9, c = i & 511;
    W1t[(size_t)c * 128 + r] = f2bf(W1[i]);
  } else if (blk < 5376) {
    int i = (blk - 4352) * 256 + tid;      // 512*512
    int r = i >> 9, c = i & 511;
    W2t[(size_t)c * 512 + r] = f2bf(W2[i]);
  } else {
    int i = (blk - 5376) * 256 + tid;      // 512*256
    int b = i >> 8, d = i & 255;
    float xv = x[i];
    size_t base = (size_t)b * 512;
    Xs[base + d]       = f2bf(xv * xv);
    Xs[base + 256 + d] = f2bf(xv);
  }
}

// raw [N][512] fp32 (mu | logvar) -> Ps [N][1024] bf16 : [hi(v) | lo(v)],
// v = [-0.5*inv_var (256), mu*inv_var (256)], plus cvec [N].
// One wave per component; float4 loads, ushort4 stores. (round-8, proven)
__global__ __launch_bounds__(256) void params_kernel(const float* __restrict__ raw,
                                                     ushort_t* __restrict__ Ps,
                                                     float* __restrict__ cvec) {
  const int w = threadIdx.x >> 6, lane = threadIdx.x & 63;
  const int n = blockIdx.x * 4 + w;
  size_t rb = (size_t)n * 512;
  float4 mu4 = *(const float4*)(raw + rb + lane * 4);
  float4 lv4 = *(const float4*)(raw + rb + 256 + lane * 4);
  float mus[4] = {mu4.x, mu4.y, mu4.z, mu4.w};
  float lvs[4] = {lv4.x, lv4.y, lv4.z, lv4.w};
  ushort4 o0, o1, o2, o3;
  ushort_t* p0 = &o0.x; ushort_t* p1 = &o1.x;
  ushort_t* p2 = &o2.x; ushort_t* p3 = &o3.x;
  float part = 0.f;
  #pragma unroll
  for (int e = 0; e < 4; e++) {
    float lv = lvs[e];
    float sp = (lv > 20.f) ? lv : log1pf(expf(lv));
    float sd = fminf(sp + 0.1f, 1.0f);
    float iv = 1.0f / (sd * sd);
    float v0 = -0.5f * iv;
    float v1 = mus[e] * iv;
    ushort_t h0 = f2bf(v0), h1 = f2bf(v1);
    p0[e] = h0; p1[e] = h1;
    p2[e] = f2bf(v0 - bf2f(h0));
    p3[e] = f2bf(v1 - bf2f(h1));
    part += -0.5f * mus[e] * mus[e] * iv - logf(sd);
  }
  size_t pb = (size_t)n * 1024;
  *(ushort4*)(Ps + pb + lane * 4)       = o0;
  *(ushort4*)(Ps + pb + 256 + lane * 4) = o1;
  *(ushort4*)(Ps + pb + 512 + lane * 4) = o2;
  *(ushort4*)(Ps + pb + 768 + lane * 4) = o3;
  #pragma unroll
  for (int off = 32; off > 0; off >>= 1) part += __shfl_down(part, off, 64);
  if (lane == 0) cvec[n] = part + NEG_HALF_D_LOG2PI;
}

// ------------------------------------------------------------------
// 256x256 bf16 MFMA GEMM — round-6/8 2-phase structure (proven).
// BK=64, 512 threads (8 waves 2x4), double-buffered 128KB LDS,
// global_load_lds 16B with pre-swizzled source, XOR swizzle, k-half
// composed via XOR. One __syncthreads per K-step.
// EPI: 0 = relu(+bias) -> bf16 out;  1 = +bias -> f32 out
// ------------------------------------------------------------------
template<int EPI>
__global__ __launch_bounds__(512, 2) void gemm256(
    const ushort_t* __restrict__ A, int lda,
    const ushort_t* __restrict__ B, int ldb,
    const float* __restrict__ bias,
    void* __restrict__ Cout, int ldc,
    int nsteps, int sps,
    int kbA0, int kbA1, int kbA2,
    int kbB0, int kbB1, int kbB2,
    int nShort, int shortIsM) {
  __shared__ __align__(16) ushort_t As[2][16384];   // 32KB per buffer
  __shared__ __align__(16) ushort_t Bs[2][16384];

  const int tid = threadIdx.x;
  const int lane = tid & 63, wid = tid >> 6;
  const int wr = wid >> 2, wc = wid & 3;            // 2 x 4 wave grid

  // XCD-chunked bijective block swizzle (gridDim.x % 8 == 0)
  const int cpx = gridDim.x >> 3;
  const int newid = (blockIdx.x & 7) * cpx + (blockIdx.x >> 3);
  const int s = newid % nShort, l = newid / nShort;
  const int m0 = (shortIsM ? s : l) * 256;
  const int n0 = (shortIsM ? l : s) * 256;

  // ---- staging: 4 rounds per matrix; dest chunk p = r*512+tid (16B) ----
  const ushort_t* pA[4];
  const ushort_t* pB[4];
  #pragma unroll
  for (int r = 0; r < 4; r++) {
    int p = r * 512 + tid;
    int row = p >> 3;
    int col = ((p & 7) ^ (row & 7)) * 8;
    pA[r] = A + (size_t)(m0 + row) * lda + col;
    pB[r] = B + (size_t)(n0 + row) * ldb + col;
  }

  // ---- fragment read byte-offsets (swizzled); k-half composed via XOR ----
  int aoff[8], boff[4];
  #pragma unroll
  for (int i = 0; i < 8; i++) {
    int ra = wr * 128 + i * 16 + (lane & 15);
    aoff[i] = (ra * 128 + ((lane >> 4) * 16)) ^ ((ra & 7) << 4);
  }
  #pragma unroll
  for (int j = 0; j < 4; j++) {
    int rb = wc * 64 + j * 16 + (lane & 15);
    boff[j] = (rb * 128 + ((lane >> 4) * 16)) ^ ((rb & 7) << 4);
  }

  f32x4 acc[8][4];
  #pragma unroll
  for (int i = 0; i < 8; i++)
    #pragma unroll
    for (int j = 0; j < 4; j++)
      acc[i][j] = (f32x4){0.f, 0.f, 0.f, 0.f};

  auto stage = [&](int buf, int step) {
    int sg = (step >= sps) ? ((step >= 2 * sps) ? 2 : 1) : 0;
    int ks = (step - sg * sps) << 6;
    int kA = ((sg == 0) ? kbA0 : (sg == 1) ? kbA1 : kbA2) + ks;
    int kB = ((sg == 0) ? kbB0 : (sg == 1) ? kbB1 : kbB2) + ks;
    #pragma unroll
    for (int r = 0; r < 4; r++) {
      load_lds16(pA[r] + kA, &As[buf][(r * 512 + tid) * 8]);
      load_lds16(pB[r] + kB, &Bs[buf][(r * 512 + tid) * 8]);
    }
  };

  stage(0, 0);
  __syncthreads();              // vmcnt drain -> buf0 ready

  int cur = 0;
  for (int step = 0; step < nsteps; ++step) {
    if (step + 1 < nsteps) stage(cur ^ 1, step + 1);   // loads fly over compute

    const char* Ab = (const char*)As[cur];
    const char* Bb = (const char*)Bs[cur];
    #pragma unroll
    for (int kh = 0; kh < 2; ++kh) {
      bf16x8 af[8], bfr[4];
      #pragma unroll
      for (int i = 0; i < 8; i++) af[i] = *(const bf16x8*)(Ab + (aoff[i] ^ (kh << 6)));
      #pragma unroll
      for (int j = 0; j < 4; j++) bfr[j] = *(const bf16x8*)(Bb + (boff[j] ^ (kh << 6)));
      #pragma unroll
      for (int i = 0; i < 8; i++)
        #pragma unroll
        for (int j = 0; j < 4; j++)
          acc[i][j] = __builtin_amdgcn_mfma_f32_16x16x32_bf16(af[i], bfr[j], acc[i][j], 0, 0, 0);
    }
    __syncthreads();            // drains vmcnt (next buf ready) + lgkm
    cur ^= 1;
  }

  // ---- epilogue ----
  float bv[4];
  #pragma unroll
  for (int j = 0; j < 4; j++)
    bv[j] = bias[n0 + wc * 64 + j * 16 + (lane & 15)];
  #pragma unroll
  for (int i = 0; i < 8; i++) {
    int rowb = m0 + wr * 128 + i * 16 + ((lane >> 4) << 2);
    #pragma unroll
    for (int r = 0; r < 4; r++) {
      #pragma unroll
      for (int j = 0; j < 4; j++) {
        int col = n0 + wc * 64 + j * 16 + (lane & 15);
        float v = acc[i][j][r] + bv[j];
        if (EPI == 0) {
          v = fmaxf(v, 0.f);
          ((ushort_t*)Cout)[(size_t)(rowb + r) * ldc + col] = f2bf(v);
        } else {
          ((float*)Cout)[(size_t)(rowb + r) * ldc + col] = v;
        }
      }
    }
  }
}

// ------------------------------------------------------------------
// Top-16: wave-cooperative ballot-filtered select (proven).
// ------------------------------------------------------------------
__device__ __forceinline__ u64_t shfl_up1_u64(u64_t v) {
  uint_t lo = (uint_t)v, hi = (uint_t)(v >> 32);
  lo = __shfl_up(lo, 1, 64); hi = __shfl_up(hi, 1, 64);
  return ((u64_t)hi << 32) | lo;
}
__device__ __forceinline__ u64_t shfl_u64(u64_t v, int src) {
  uint_t lo = (uint_t)v, hi = (uint_t)(v >> 32);
  lo = __shfl(lo, src, 64); hi = __shfl(hi, src, 64);
  return ((u64_t)hi << 32) | lo;
}
__device__ __forceinline__ void insert_step(u64_t& key, u64_t cand, int lane) {
  u64_t kup = shfl_up1_u64(key);
  if (lane == 0) kup = ~0ULL;
  if (cand > key) key = (cand > kup) ? kup : cand;
}

__global__ __launch_bounds__(256) void topk_kernel(const float* __restrict__ lp,
                                                   const float* __restrict__ log_w,
                                                   float* __restrict__ out) {
  const int b = blockIdx.x;
  const int tid = threadIdx.x;
  const int w = tid >> 6, lane = tid & 63;
  const float* row = lp + (size_t)b * NCOMP;

  u64_t key = 0;
  u64_t theta = 0;

  const int base = w * 8192;
  for (int c = 0; c < 32; ++c) {
    int n0 = base + c * 256 + lane * 4;
    float4 s4 = *(const float4*)&row[n0];
    float4 w4 = *(const float4*)&log_w[n0];
    float ss[4] = {s4.x + w4.x, s4.y + w4.y, s4.z + w4.z, s4.w + w4.w};
    #pragma unroll
    for (int e = 0; e < 4; e++) {
      uint_t u = __float_as_uint(ss[e]);
      u = (u & 0x80000000u) ? ~u : (u | 0x80000000u);
      u64_t k = ((u64_t)u << 32) | (u64_t)(0xFFFFFFFFu - (uint_t)(n0 + e));
      u64_t m = __ballot(k > theta);
      if (m) {
        do {
          int src = __ffsll((long long)m) - 1;
          m &= m - 1;
          u64_t cand = shfl_u64(k, src);
          insert_step(key, cand, lane);
        } while (m);
        theta = shfl_u64(key, 15);
      }
    }
  }

  __shared__ u64_t sk[64];
  if (lane < 16) sk[w * 16 + lane] = key;
  __syncthreads();
  if (w == 0) {
    u64_t th = shfl_u64(key, 15);
    for (int t = 16; t < 64; ++t) {
      u64_t cand = sk[t];
      if (cand > th) {
        insert_step(key, cand, lane);
        th = shfl_u64(key, 15);
      }
    }
    if (lane < 16) {
      uint_t idx = 0xFFFFFFFFu - (uint_t)key;
      out[(size_t)b * KTOP + lane] = row[idx];
    }
  }
}

// ------------------------------------------------------------------
extern "C" void kernel_launch(void* const* d_in, const int* in_sizes, int n_in,
                              void* d_out, int out_size, void* d_ws, size_t ws_size,
                              hipStream_t stream) {
  const float* x     = (const float*)d_in[0];
  const float* log_w = (const float*)d_in[1];
  const float* z     = (const float*)d_in[2];
  const float* W1    = (const float*)d_in[3];
  const float* b1    = (const float*)d_in[4];
  const float* W2    = (const float*)d_in[5];
  const float* b2    = (const float*)d_in[6];
  float* out = (float*)d_out;

  char* p = (char*)d_ws;
  float* raw   = (float*)p;    p += (size_t)NCOMP * 512 * 4;   // 64MB (reused as lp)
  float* cvec  = (float*)p;    p += (size_t)NCOMP * 4;
  ushort_t* Ps = (ushort_t*)p; p += (size_t)NCOMP * 1024 * 2;  // 64MB
  ushort_t* h16= (ushort_t*)p; p += (size_t)NCOMP * 512 * 2;   // 32MB
  ushort_t* z16= (ushort_t*)p; p += (size_t)NCOMP * 128 * 2;   // 8MB
  ushort_t* W1t= (ushort_t*)p; p += (size_t)512 * 128 * 2;
  ushort_t* W2t= (ushort_t*)p; p += (size_t)512 * 512 * 2;
  ushort_t* Xs = (ushort_t*)p; p += (size_t)512 * 512 * 2;
  float* lp = raw;

  // prep (merged, round-8 layouts): z16, W1t, W2t, Xs
  hipLaunchKernelGGL(prep_kernel, dim3(5888), dim3(256), 0, stream,
                     x, z, W1, W2, z16, W1t, W2t, Xs);

  // G1: h16 = relu(z16 @ W1t^T + b1)   [32768,128] x [512,128]^T
  hipLaunchKernelGGL((gemm256<0>), dim3(256), dim3(512), 0, stream,
                     z16, LDIM, W1t, LDIM, b1, h16, HDIM,
                     2, 2, 0, 0, 0, 0, 0, 0, 2, 0);
  // G2: raw = h16 @ W2t^T + b2         [32768,512] x [512,512]^T
  hipLaunchKernelGGL((gemm256<1>), dim3(256), dim3(512), 0, stream,
                     h16, HDIM, W2t, HDIM, b2, raw, HDIM,
                     8, 8, 0, 0, 0, 0, 0, 0, 2, 0);
  // params: raw -> Ps (split hi/lo), cvec
  hipLaunchKernelGGL(params_kernel, dim3(NCOMP / 4), dim3(256), 0, stream,
                     raw, Ps, cvec);
  // G3: lp = Xs @ Ps^T + cvec  (split-bf16, A-lo dropped: uh*vh + uh*vl)
  //     K=1024: A segs {0,0} (hi,hi); B segs {0,512} (hi,lo); nt=16
  hipLaunchKernelGGL((gemm256<1>), dim3(256), dim3(512), 0, stream,
                     Xs, 512, Ps, 1024, cvec, lp, NCOMP,
                     16, 8, 0, 0, 0, 0, 512, 0, 2, 1);
  // topk
  hipLaunchKernelGGL(topk_kernel, dim3(BROWS), dim3(256), 0, stream, lp, log_w, out);
}